// Round 1
// baseline (333.324 us; speedup 1.0000x reference)
//
#include <hip/hip_runtime.h>
#include <hip/hip_bf16.h>

typedef __bf16 bf16x8 __attribute__((ext_vector_type(8)));
typedef float  f32x4  __attribute__((ext_vector_type(4)));
typedef float  float4v __attribute__((ext_vector_type(4)));
typedef short  short4v __attribute__((ext_vector_type(4)));

#define BM 128
#define BN 128
#define BKK 64

static constexpr int Tn   = 2048;
static constexpr int Bn   = 16;
static constexpr int Cn   = 768;
static constexpr int NQKV = 3 * Cn;  // 2304

__device__ __forceinline__ void gload_lds16(const void* g, void* l) {
  __builtin_amdgcn_global_load_lds((const __attribute__((address_space(1))) void*)g,
                                   (__attribute__((address_space(3))) void*)l, 16, 0, 0);
}

// stage a 128x64 bf16 tile (row-major in LDS, global row stride = 768 bf16)
__device__ __forceinline__ void stage_tile(const char* gbase, __bf16* lds, int t) {
#pragma unroll
  for (int i = 0; i < 4; ++i) {
    int O   = i * 4096 + t * 16;
    int row = O >> 7;     // 128 bytes per LDS row
    int cb  = O & 127;
    gload_lds16(gbase + (size_t)row * 1536 + cb, (char*)lds + O);
  }
}

// ---------------- fused QKV projection: C1[m][n] = sum_c X[m][c]*W[n][c] + bias[n]
__global__ __launch_bounds__(256, 2)
void proj_kernel(const __bf16* __restrict__ X, const __bf16* __restrict__ W,
                 const float* __restrict__ bias,
                 __hip_bfloat16* __restrict__ Q, __hip_bfloat16* __restrict__ Kb,
                 __hip_bfloat16* __restrict__ V)
{
  __shared__ __bf16 As[BM * BKK];
  __shared__ __bf16 Bs[BN * BKK];
  const int t      = threadIdx.x;
  const int tile_n = blockIdx.x * BN;
  const int tile_m = blockIdx.y * BM;
  const int lane   = t & 63;
  const int wv     = t >> 6;
  const int wm     = wv >> 1, wn = wv & 1;
  const int lrow   = lane & 15;
  const int lk8    = (lane >> 4) * 8;

  const char* Ab = (const char*)(X + (size_t)tile_m * Cn);
  const char* Bb = (const char*)(W + (size_t)tile_n * Cn);

  f32x4 acc[4][4] = {};

  for (int k0 = 0; k0 < Cn; k0 += BKK) {
    stage_tile(Ab + (size_t)k0 * 2, As, t);
    stage_tile(Bb + (size_t)k0 * 2, Bs, t);
    __syncthreads();
#pragma unroll
    for (int ks = 0; ks < 2; ++ks) {
      bf16x8 a[4], b[4];
#pragma unroll
      for (int mi = 0; mi < 4; ++mi)
        a[mi] = *(const bf16x8*)&As[(wm * 64 + mi * 16 + lrow) * BKK + ks * 32 + lk8];
#pragma unroll
      for (int ni = 0; ni < 4; ++ni)
        b[ni] = *(const bf16x8*)&Bs[(wn * 64 + ni * 16 + lrow) * BKK + ks * 32 + lk8];
#pragma unroll
      for (int mi = 0; mi < 4; ++mi)
#pragma unroll
        for (int ni = 0; ni < 4; ++ni)
          acc[mi][ni] = __builtin_amdgcn_mfma_f32_16x16x32_bf16(a[mi], b[ni], acc[mi][ni], 0, 0, 0);
    }
    __syncthreads();
  }

  // epilogue: add bias, write bf16 into Q/K/V (block's 128-col span stays in one buffer)
  const int which = tile_n / Cn;
  const int nbase = tile_n - which * Cn;
  __hip_bfloat16* outb = (which == 0) ? Q : (which == 1 ? Kb : V);
  const int crow = (lane >> 4) * 4;
#pragma unroll
  for (int ni = 0; ni < 4; ++ni) {
    const int coff = wn * 64 + ni * 16 + lrow;
    const float bb = bias[tile_n + coff];
    const int d    = nbase + coff;
#pragma unroll
    for (int mi = 0; mi < 4; ++mi) {
#pragma unroll
      for (int r = 0; r < 4; ++r) {
        const int gm = tile_m + wm * 64 + mi * 16 + crow + r;
        outb[(size_t)gm * Cn + d] = __float2bfloat16(acc[mi][ni][r] + bb);
      }
    }
  }
}

// ---------------- attention colsum: w[b,k'] += sum_q sigmoid(scale * Q_q . K_k')
__global__ __launch_bounds__(256, 2)
void attn_kernel(const __bf16* __restrict__ Q, const __bf16* __restrict__ K,
                 float* __restrict__ wsum)
{
  __shared__ __bf16 As[BM * BKK];
  __shared__ __bf16 Bs[BN * BKK];
  const int t    = threadIdx.x;
  const int kt   = blockIdx.x, qt = blockIdx.y, b = blockIdx.z;
  const int lane = t & 63;
  const int wv   = t >> 6;
  const int wm   = wv >> 1, wn = wv & 1;
  const int lrow = lane & 15;
  const int lk8  = (lane >> 4) * 8;

  const char* Ab = (const char*)(Q + ((size_t)b * Tn + qt * BM) * Cn);
  const char* Bb = (const char*)(K + ((size_t)b * Tn + kt * BN) * Cn);

  f32x4 acc[4][4] = {};

  for (int k0 = 0; k0 < Cn; k0 += BKK) {
    stage_tile(Ab + (size_t)k0 * 2, As, t);
    stage_tile(Bb + (size_t)k0 * 2, Bs, t);
    __syncthreads();
#pragma unroll
    for (int ks = 0; ks < 2; ++ks) {
      bf16x8 a[4], bfr[4];
#pragma unroll
      for (int mi = 0; mi < 4; ++mi)
        a[mi] = *(const bf16x8*)&As[(wm * 64 + mi * 16 + lrow) * BKK + ks * 32 + lk8];
#pragma unroll
      for (int ni = 0; ni < 4; ++ni)
        bfr[ni] = *(const bf16x8*)&Bs[(wn * 64 + ni * 16 + lrow) * BKK + ks * 32 + lk8];
#pragma unroll
      for (int mi = 0; mi < 4; ++mi)
#pragma unroll
        for (int ni = 0; ni < 4; ++ni)
          acc[mi][ni] = __builtin_amdgcn_mfma_f32_16x16x32_bf16(a[mi], bfr[ni], acc[mi][ni], 0, 0, 0);
    }
    __syncthreads();
  }

  const float scale = 0.036084391824351615f;  // 1/sqrt(768)
  float csum[4] = {0.f, 0.f, 0.f, 0.f};
#pragma unroll
  for (int ni = 0; ni < 4; ++ni)
#pragma unroll
    for (int mi = 0; mi < 4; ++mi)
#pragma unroll
      for (int r = 0; r < 4; ++r) {
        float s = acc[mi][ni][r] * scale;
        csum[ni] += 1.f / (1.f + __expf(-s));
      }
#pragma unroll
  for (int ni = 0; ni < 4; ++ni) {
    csum[ni] += __shfl_xor(csum[ni], 16);
    csum[ni] += __shfl_xor(csum[ni], 32);
  }
  if (lane < 16) {
#pragma unroll
    for (int ni = 0; ni < 4; ++ni)
      atomicAdd(&wsum[(size_t)b * Tn + kt * BN + wn * 64 + ni * 16 + lane], csum[ni]);
  }
}

// ---------------- out_pre[b,d] = (1/T) sum_k w[b,k] * V[b,k,d]
__global__ void wv_kernel(const float* __restrict__ wsum, const __bf16* __restrict__ V,
                          float* __restrict__ out_pre)
{
  const int b = blockIdx.x, dc = blockIdx.y, kc = blockIdx.z;
  const int d = dc * 256 + threadIdx.x;
  const __bf16* Vb = V + ((size_t)b * Tn + kc * 256) * Cn + d;
  const float* wb  = wsum + (size_t)b * Tn + kc * 256;
  float acc = 0.f;
#pragma unroll 8
  for (int k = 0; k < 256; ++k)
    acc += wb[k] * (float)Vb[(size_t)k * Cn];
  atomicAdd(&out_pre[b * Cn + d], acc * (1.f / 2048.f));
}

// ---------------- BatchNorm1d over batch dim (training stats, biased var)
__global__ void bn_kernel(const float* __restrict__ out_pre,
                          const float* __restrict__ gamma, const float* __restrict__ beta,
                          float* __restrict__ out)
{
  const int d = blockIdx.x * 256 + threadIdx.x;  // 768 columns
  float vals[16];
  float s = 0.f;
#pragma unroll
  for (int b = 0; b < 16; ++b) { vals[b] = out_pre[b * Cn + d]; s += vals[b]; }
  const float mu = s * (1.f / 16.f);
  float s2 = 0.f;
#pragma unroll
  for (int b = 0; b < 16; ++b) { float t2 = vals[b] - mu; s2 += t2 * t2; }
  const float inv = rsqrtf(s2 * (1.f / 16.f) + 1e-5f);
  const float g = gamma[d] * inv, be = beta[d];
#pragma unroll
  for (int b = 0; b < 16; ++b) out[b * Cn + d] = (vals[b] - mu) * g + be;
}

// ---------------- conversions
__global__ void cvt_x_kernel(const float* __restrict__ x, __hip_bfloat16* __restrict__ xb, int n4)
{
  int i = blockIdx.x * blockDim.x + threadIdx.x;
  if (i >= n4) return;
  float4v v = ((const float4v*)x)[i];
  short4v o;
#pragma unroll
  for (int j = 0; j < 4; ++j) o[j] = __builtin_bit_cast(short, __float2bfloat16(v[j]));
  ((short4v*)xb)[i] = o;
}

__global__ void cvt_w_kernel(const float* __restrict__ Wq, const float* __restrict__ Wk,
                             const float* __restrict__ Wv,
                             const float* __restrict__ bq, const float* __restrict__ bk,
                             const float* __restrict__ bv,
                             __hip_bfloat16* __restrict__ Wc, float* __restrict__ biasc)
{
  int idx = blockIdx.x * 256 + threadIdx.x;
  if (idx >= NQKV * Cn) return;
  int n = idx / Cn, c = idx - n * Cn;
  const float* W;
  const float* bb;
  int nn;
  if (n < Cn)            { W = Wq; bb = bq; nn = n; }
  else if (n < 2 * Cn)   { W = Wk; bb = bk; nn = n - Cn; }
  else                   { W = Wv; bb = bv; nn = n - 2 * Cn; }
  Wc[idx] = __float2bfloat16(W[(size_t)nn * Cn + c]);
  if (c == 0) biasc[n] = bb[nn];
}

extern "C" void kernel_launch(void* const* d_in, const int* in_sizes, int n_in,
                              void* d_out, int out_size, void* d_ws, size_t ws_size,
                              hipStream_t stream)
{
  const float* x  = (const float*)d_in[0];
  const float* Wq = (const float*)d_in[1];
  const float* bq = (const float*)d_in[2];
  const float* Wk = (const float*)d_in[3];
  const float* bk = (const float*)d_in[4];
  const float* Wv = (const float*)d_in[5];
  const float* bv = (const float*)d_in[6];
  const float* gamma = (const float*)d_in[7];
  const float* beta  = (const float*)d_in[8];
  float* out = (float*)d_out;

  char* ws = (char*)d_ws;
  // workspace layout (total ~195.6 MiB)
  __hip_bfloat16* xb  = (__hip_bfloat16*)(ws);                  // 32768*768*2 = 50,331,648
  __hip_bfloat16* Wc  = (__hip_bfloat16*)(ws + 50331648);       // 2304*768*2  =  3,538,944
  float*          bc  = (float*)         (ws + 53870592);       // 2304*4      =      9,216
  __hip_bfloat16* Qb  = (__hip_bfloat16*)(ws + 53879808);       // 50,331,648
  __hip_bfloat16* Kb  = (__hip_bfloat16*)(ws + 104211456);      // 50,331,648
  __hip_bfloat16* Vb  = (__hip_bfloat16*)(ws + 154543104);      // 50,331,648
  float*          wsum= (float*)         (ws + 204874752);      // 16*2048*4   =    131,072
  float*          opre= (float*)         (ws + 205005824);      // 16*768*4    =     49,152

  (void)in_sizes; (void)n_in; (void)out_size; (void)ws_size;

  hipMemsetAsync(wsum, 0, 131072 + 49152, stream);  // wsum + out_pre (contiguous)

  cvt_x_kernel<<<dim3(24576), 256, 0, stream>>>(x, xb, 25165824 / 4);
  cvt_w_kernel<<<dim3(6912), 256, 0, stream>>>(Wq, Wk, Wv, bq, bk, bv, Wc, bc);

  proj_kernel<<<dim3(NQKV / BN, (Bn * Tn) / BM), 256, 0, stream>>>(
      (const __bf16*)xb, (const __bf16*)Wc, bc, Qb, Kb, Vb);

  attn_kernel<<<dim3(Tn / BN, Tn / BM, Bn), 256, 0, stream>>>(
      (const __bf16*)Qb, (const __bf16*)Kb, wsum);

  wv_kernel<<<dim3(Bn, 3, 8), 256, 0, stream>>>(wsum, (const __bf16*)Vb, opre);

  bn_kernel<<<dim3(3), 256, 0, stream>>>(opre, gamma, beta, out);
}